// Round 3
// baseline (303.486 us; speedup 1.0000x reference)
//
#include <hip/hip_runtime.h>

// GCN: h1 = relu(agg(x@W1)); h2 = relu(agg(h1@W2)); out = h2@Wfc + bfc
// agg_i = dinv_i * (y_i + sum_{j in N(i)} y_j) + b, where y = (x@W)*dinv[:,None],
// dinv_i = rsqrt(indeg_i + 1).
// Graph built per launch as an EXACT uint16 CSR (hist -> scan -> fill):
// csr footprint 1.6 MB (vs 12.8 MB CAP-padded int32) to minimize scattered
// partial-line HBM write-backs (round-2 k_fill: 48 MB WRITE_SIZE = the bottleneck).

__global__ __launch_bounds__(256) void k_zero(int* __restrict__ p, int n) {
    int i = blockIdx.x * 256 + threadIdx.x;
    if (i < n) p[i] = 0;
}

__global__ __launch_bounds__(256) void k_hist(const int* __restrict__ dst,
                                              int* __restrict__ cnt, int E) {
    int e = blockIdx.x * 256 + threadIdx.x;
    if (e < E) atomicAdd(&cnt[dst[e]], 1);
}

// per-block exclusive scan of cnt -> off, block sums -> bsum
__global__ __launch_bounds__(256) void k_scan1(const int* __restrict__ cnt,
                                               int* __restrict__ off,
                                               int* __restrict__ bsum, int n) {
    __shared__ int s[256];
    int tid = threadIdx.x;
    int i = blockIdx.x * 256 + tid;
    int v = (i < n) ? cnt[i] : 0;
    s[tid] = v;
    __syncthreads();
#pragma unroll
    for (int d = 1; d < 256; d <<= 1) {
        int t = (tid >= d) ? s[tid - d] : 0;
        __syncthreads();
        s[tid] += t;
        __syncthreads();
    }
    if (i < n) off[i] = s[tid] - v;
    if (tid == 255) bsum[blockIdx.x] = s[255];
}

// exclusive scan of bsum in-place (single block; nb <= 256)
__global__ __launch_bounds__(256) void k_scan2(int* __restrict__ bsum, int nb) {
    __shared__ int s[256];
    int tid = threadIdx.x;
    int v = (tid < nb) ? bsum[tid] : 0;
    s[tid] = v;
    __syncthreads();
#pragma unroll
    for (int d = 1; d < 256; d <<= 1) {
        int t = (tid >= d) ? s[tid - d] : 0;
        __syncthreads();
        s[tid] += t;
        __syncthreads();
    }
    if (tid < nb) bsum[tid] = s[tid] - v;
}

// add block bases; also seed fill cursors
__global__ __launch_bounds__(256) void k_scan3(int* __restrict__ off,
                                               int* __restrict__ cur,
                                               const int* __restrict__ bsum, int n) {
    int i = blockIdx.x * 256 + threadIdx.x;
    if (i < n) {
        int o = off[i] + bsum[blockIdx.x];
        off[i] = o;
        cur[i] = o;
    }
}

__global__ __launch_bounds__(256) void k_fill(const int* __restrict__ src,
                                              const int* __restrict__ dst,
                                              int* __restrict__ cur,
                                              unsigned short* __restrict__ csr, int E) {
    int e = blockIdx.x * 256 + threadIdx.x;
    if (e >= E) return;
    int d = dst[e];
    int p = atomicAdd(&cur[d], 1);
    csr[p] = (unsigned short)src[e];
}

// Y[row][c] = dinv[row] * sum_k X[row][k] * W[k][c];  64 output cols.
// 64-row x 64-col tile, 256 threads (4 waves), 4x4 register tile per thread.
template <int K>
__global__ __launch_bounds__(256) void k_gemm(const float* __restrict__ X,
                                              const float* __restrict__ W,
                                              const int* __restrict__ cnt,
                                              float* __restrict__ Y, int n) {
    constexpr int KC = 64;
    constexpr int XS = KC + 4;
    __shared__ float ws[KC * 64];     // 16 KB
    __shared__ float xs[64 * XS];     // 17 KB
    const int tid = threadIdx.x;
    const int tx = tid & 15;
    const int ty = tid >> 4;
    const int row0 = blockIdx.x * 64;

    float acc[4][4];
#pragma unroll
    for (int r = 0; r < 4; r++)
#pragma unroll
        for (int c = 0; c < 4; c++) acc[r][c] = 0.f;

    for (int kc = 0; kc < K; kc += KC) {
        for (int i = tid; i < KC * 16; i += 256) {
            int kk = i >> 4, c4 = i & 15;
            *(float4*)&ws[kk * 64 + 4 * c4] = *(const float4*)&W[(kc + kk) * 64 + 4 * c4];
        }
        for (int i = tid; i < 64 * (KC / 4); i += 256) {
            int r = i / (KC / 4), q = i % (KC / 4);
            float4 v = make_float4(0.f, 0.f, 0.f, 0.f);
            int row = row0 + r;
            if (row < n) v = *(const float4*)&X[(size_t)row * K + kc + 4 * q];
            *(float4*)&xs[r * XS + 4 * q] = v;
        }
        __syncthreads();

        for (int q = 0; q < KC / 4; q++) {
            float4 xv[4];
#pragma unroll
            for (int r = 0; r < 4; r++)
                xv[r] = *(const float4*)&xs[(ty + 16 * r) * XS + 4 * q];
#pragma unroll
            for (int kk = 0; kk < 4; kk++) {
                float4 wv = *(const float4*)&ws[(4 * q + kk) * 64 + 4 * tx];
#pragma unroll
                for (int r = 0; r < 4; r++) {
                    float xval = (kk == 0) ? xv[r].x : (kk == 1) ? xv[r].y
                               : (kk == 2) ? xv[r].z : xv[r].w;
                    acc[r][0] = fmaf(xval, wv.x, acc[r][0]);
                    acc[r][1] = fmaf(xval, wv.y, acc[r][1]);
                    acc[r][2] = fmaf(xval, wv.z, acc[r][2]);
                    acc[r][3] = fmaf(xval, wv.w, acc[r][3]);
                }
            }
        }
        __syncthreads();
    }

#pragma unroll
    for (int r = 0; r < 4; r++) {
        int row = row0 + ty + 16 * r;
        if (row < n) {
            float d = rsqrtf((float)cnt[row] + 1.0f);
            float4 o;
            o.x = acc[r][0] * d; o.y = acc[r][1] * d;
            o.z = acc[r][2] * d; o.w = acc[r][3] * d;
            *(float4*)&Y[(size_t)row * 64 + 4 * tx] = o;
        }
    }
}

// out[i][c] = relu( dinv_i * (y[i][c] + sum_j y[j][c]) + bias[c] )
// one wave per node, lane = feature channel; 8x-unrolled gather for MLP.
__global__ __launch_bounds__(256) void k_agg(const float* __restrict__ y,
                                             const unsigned short* __restrict__ csr,
                                             const int* __restrict__ off,
                                             const int* __restrict__ cnt,
                                             const float* __restrict__ bias,
                                             float* __restrict__ out, int n) {
    int node = (blockIdx.x * 256 + threadIdx.x) >> 6;
    int lane = threadIdx.x & 63;
    if (node >= n) return;
    int deg = cnt[node];
    const unsigned short* lst = csr + off[node];
    float acc = y[node * 64 + lane];  // self term
    int i = 0;
    for (; i + 8 <= deg; i += 8) {
        int j0 = lst[i];     int j1 = lst[i + 1];
        int j2 = lst[i + 2]; int j3 = lst[i + 3];
        int j4 = lst[i + 4]; int j5 = lst[i + 5];
        int j6 = lst[i + 6]; int j7 = lst[i + 7];
        float v0 = y[j0 * 64 + lane];
        float v1 = y[j1 * 64 + lane];
        float v2 = y[j2 * 64 + lane];
        float v3 = y[j3 * 64 + lane];
        float v4 = y[j4 * 64 + lane];
        float v5 = y[j5 * 64 + lane];
        float v6 = y[j6 * 64 + lane];
        float v7 = y[j7 * 64 + lane];
        acc += ((v0 + v1) + (v2 + v3)) + ((v4 + v5) + (v6 + v7));
    }
    if (i + 4 <= deg) {
        int j0 = lst[i];     int j1 = lst[i + 1];
        int j2 = lst[i + 2]; int j3 = lst[i + 3];
        float v0 = y[j0 * 64 + lane];
        float v1 = y[j1 * 64 + lane];
        float v2 = y[j2 * 64 + lane];
        float v3 = y[j3 * 64 + lane];
        acc += (v0 + v1) + (v2 + v3);
        i += 4;
    }
    for (; i < deg; i++) acc += y[lst[i] * 64 + lane];
    float d = rsqrtf((float)deg + 1.0f);
    float v = fmaf(d, acc, bias[lane]);
    out[node * 64 + lane] = fmaxf(v, 0.f);
}

// out[i][c] = sum_k h[i][k] * Wfc[k][c] + bfc[c],  c < 12
__global__ __launch_bounds__(256) void k_fc(const float* __restrict__ h,
                                            const float* __restrict__ Wfc,
                                            const float* __restrict__ bfc,
                                            float* __restrict__ out, int n) {
    __shared__ float hs[64 * 64];
    __shared__ float wf[64 * 12];
    __shared__ float bf[12];
    int tid = threadIdx.x;
    int node0 = blockIdx.x * 64;
    for (int i = tid; i < 64 * 12; i += 256) wf[i] = Wfc[i];
    if (tid < 12) bf[tid] = bfc[tid];
    for (int f = tid; f < 1024; f += 256) {
        int r = f >> 4, c4 = f & 15;
        float4 v = make_float4(0.f, 0.f, 0.f, 0.f);
        if (node0 + r < n) v = *(const float4*)&h[(size_t)(node0 + r) * 64 + 4 * c4];
        *(float4*)&hs[r * 64 + 4 * c4] = v;
    }
    __syncthreads();
    for (int o = tid; o < 64 * 12; o += 256) {
        int r = o / 12, c = o % 12;
        if (node0 + r >= n) continue;
        float acc = bf[c];
        for (int k = 0; k < 64; k++) acc = fmaf(hs[r * 64 + k], wf[k * 12 + c], acc);
        out[(size_t)(node0 + r) * 12 + c] = acc;
    }
}

extern "C" void kernel_launch(void* const* d_in, const int* in_sizes, int n_in,
                              void* d_out, int out_size, void* d_ws, size_t ws_size,
                              hipStream_t stream) {
    const float* x   = (const float*)d_in[0];
    const int*   ei  = (const int*)d_in[1];
    const float* W1  = (const float*)d_in[2];
    const float* b1  = (const float*)d_in[3];
    const float* W2  = (const float*)d_in[4];
    const float* b2  = (const float*)d_in[5];
    const float* Wfc = (const float*)d_in[6];
    const float* bfc = (const float*)d_in[7];
    float* out = (float*)d_out;

    const int n = in_sizes[0] / 128;   // 50000
    const int E = in_sizes[1] / 2;     // 800000
    const int* src = ei;
    const int* dst = ei + E;
    const int nb = (n + 255) / 256;    // 196 scan blocks

    // workspace layout (256B-aligned chunks)
    char* w = (char*)d_ws;
    int* cnt  = (int*)w;  w += (size_t)((n + 63) / 64) * 64 * 4;
    int* off  = (int*)w;  w += (size_t)((n + 63) / 64) * 64 * 4;
    int* cur  = (int*)w;  w += (size_t)((n + 63) / 64) * 64 * 4;
    int* bsum = (int*)w;  w += 256 * 4;
    unsigned short* csr = (unsigned short*)w;
    w += (size_t)((E + 127) / 128) * 128 * 2;                      // 1.6 MB
    float* y = (float*)w; w += (size_t)n * 64 * 4;                 // 12.8 MB
    float* h = (float*)w;                                          // 12.8 MB

    k_zero <<<dim3(nb), dim3(256), 0, stream>>>(cnt, n);
    k_hist <<<dim3((E + 255) / 256), dim3(256), 0, stream>>>(dst, cnt, E);
    k_scan1<<<dim3(nb), dim3(256), 0, stream>>>(cnt, off, bsum, n);
    k_scan2<<<dim3(1), dim3(256), 0, stream>>>(bsum, nb);
    k_scan3<<<dim3(nb), dim3(256), 0, stream>>>(off, cur, bsum, n);
    k_fill <<<dim3((E + 255) / 256), dim3(256), 0, stream>>>(src, dst, cur, csr, E);
    k_gemm<128><<<dim3((n + 63) / 64), dim3(256), 0, stream>>>(x, W1, cnt, y, n);
    k_agg  <<<dim3((n + 3) / 4), dim3(256), 0, stream>>>(y, csr, off, cnt, b1, h, n);
    k_gemm<64><<<dim3((n + 63) / 64), dim3(256), 0, stream>>>(h, W2, cnt, y, n);
    k_agg  <<<dim3((n + 3) / 4), dim3(256), 0, stream>>>(y, csr, off, cnt, b2, h, n);
    k_fc   <<<dim3((n + 63) / 64), dim3(256), 0, stream>>>(h, Wfc, bfc, out, n);
}